// Round 1
// baseline (352.732 us; speedup 1.0000x reference)
//
#include <hip/hip_runtime.h>
#include <hip/hip_bf16.h>
#include <math.h>

// One thread per row (8 contiguous fp32). Two float4 loads per thread = 32 B/row.
// Memory-bound: ~302 MB traffic / launch -> ~48 us roofline at 6.3 TB/s.
__global__ __launch_bounds__(256) void Expression_82643760709953_kernel(
    const float4* __restrict__ in4, float* __restrict__ out, int n_rows) {
    int idx = blockIdx.x * blockDim.x + threadIdx.x;
    int stride = gridDim.x * blockDim.x;
    for (int i = idx; i < n_rows; i += stride) {
        float4 a = in4[2 * i];       // x0 x1 x2 x3
        float4 b = in4[2 * i + 1];   // x4 x5 x6 x7
        float x0 = a.x, x1 = a.y, x2 = a.z, x3 = a.w;
        float x4 = b.x, x5 = b.y, x6 = b.z, x7 = b.w;
        float expr = (x0 * x1 + __sinf(x2)) * __expf(-fabsf(x3))
                   + x4 / (x5 * x5 + __expf(x6))
                   - x7;
        out[i] = tanhf(expr);
    }
}

extern "C" void kernel_launch(void* const* d_in, const int* in_sizes, int n_in,
                              void* d_out, int out_size, void* d_ws, size_t ws_size,
                              hipStream_t stream) {
    const float4* in4 = (const float4*)d_in[0];
    float* out = (float*)d_out;
    int n_rows = out_size;  // 8388608
    int block = 256;
    int grid = (n_rows + block - 1) / block;  // 32768 blocks
    Expression_82643760709953_kernel<<<grid, block, 0, stream>>>(in4, out, n_rows);
}

// Round 2
// 352.512 us; speedup vs baseline: 1.0006x; 1.0006x over previous
//
#include <hip/hip_runtime.h>
#include <hip/hip_bf16.h>
#include <math.h>

// One thread per row (8 contiguous fp32). Two float4 loads per thread = 32 B/row.
// Memory-bound target: ~302 MB traffic / launch -> ~48 us roofline at 6.3 TB/s.
// All transcendentals via native HW ops (v_exp_f32 / v_sin_f32 / v_rcp_f32):
// absmax threshold is 2e-2, precise libm tanh/fdiv were costing ~2x the roofline.

__device__ __forceinline__ float fast_rcp(float x) {
    return __builtin_amdgcn_rcpf(x);
}

// tanh(x) = sign(x) * (1 - 2e/(1+e)), e = exp(-2|x|).
// Large |x|: e underflows to 0 -> result +/-1 exactly. No branches.
__device__ __forceinline__ float fast_tanh(float x) {
    float a = fabsf(x);
    float e = __expf(-2.0f * a);          // v_mul + v_mul(log2e) + v_exp
    float r = fast_rcp(1.0f + e);         // v_add + v_rcp
    float t = __builtin_fmaf(-(e + e), r, 1.0f);
    return copysignf(t, x);               // 2 bit ops
}

__global__ __launch_bounds__(256) void Expression_82643760709953_kernel(
    const float4* __restrict__ in4, float* __restrict__ out, int n_rows) {
    int idx = blockIdx.x * blockDim.x + threadIdx.x;
    int stride = gridDim.x * blockDim.x;
    for (int i = idx; i < n_rows; i += stride) {
        float4 a = in4[2 * i];       // x0 x1 x2 x3
        float4 b = in4[2 * i + 1];   // x4 x5 x6 x7
        float s  = __sinf(a.z);                              // native v_sin
        float e3 = __expf(-fabsf(a.w));                      // native v_exp
        float t1 = __builtin_fmaf(a.x, a.y, s) * e3;         // (x0*x1+sin(x2))*exp(-|x3|)
        float den = __builtin_fmaf(b.y, b.y, __expf(b.z));   // x5*x5 + exp(x6)
        float t2 = b.x * fast_rcp(den);                      // x4 / den via v_rcp
        float expr = t1 + t2 - b.w;
        out[i] = fast_tanh(expr);
    }
}

extern "C" void kernel_launch(void* const* d_in, const int* in_sizes, int n_in,
                              void* d_out, int out_size, void* d_ws, size_t ws_size,
                              hipStream_t stream) {
    const float4* in4 = (const float4*)d_in[0];
    float* out = (float*)d_out;
    int n_rows = out_size;  // 8388608
    int block = 256;
    int grid = (n_rows + block - 1) / block;  // 32768 blocks
    Expression_82643760709953_kernel<<<grid, block, 0, stream>>>(in4, out, n_rows);
}